// Round 9
// baseline (725.165 us; speedup 1.0000x reference)
//
#include <hip/hip_runtime.h>
#include <math.h>

#define VOCAB 8000
#define BATCH 128
#define TMAX  512
#define DIM   256
#define HID   128
#define G4    512     // 4*HID
#define NCOL  1024    // 2*G4 (both directions)

typedef float v2f __attribute__((ext_vector_type(2)));

__device__ __forceinline__ v2f fma2(v2f a, v2f b, v2f c) {
#if __has_builtin(__builtin_elementwise_fma)
  return __builtin_elementwise_fma(a, b, c);
#else
  v2f r; r.x = fmaf(a.x, b.x, c.x); r.y = fmaf(a.y, b.y, c.y); return r;
#endif
}

// ---------------------------------------------------------------------------
// Kernel 1: embW[v][n] = emb[v,:] . W_ih_dir[n,:] + b_ih_dir[n] + b_hh_dir[n]
// Inner loop upgraded to packed v2f FMA (v_pk_fma_f32); per-element chain
// order identical to the scalar version (acc2[i][jj].{x,y} == acc[i][2jj(+1)]).
// ---------------------------------------------------------------------------
__global__ __launch_bounds__(256) void embw_gemm(
    const float* __restrict__ emb,
    const float* __restrict__ Wf, const float* __restrict__ Wb,
    const float* __restrict__ bihf, const float* __restrict__ bhhf,
    const float* __restrict__ bihb, const float* __restrict__ bhhb,
    float* __restrict__ embW) {
  __shared__ float As[32][132];   // k-major, padded stride
  __shared__ float Bs[32][132];
  const int tid = threadIdx.x;
  const int m0 = blockIdx.x * 128;
  const int n0 = blockIdx.y * 128;
  const int tx = tid & 15, ty = tid >> 4;
  const int lrow = tid >> 1;            // 0..127
  const int lseg = (tid & 1) * 16;      // 0 or 16 (k offset)
  const float* Wsrc = (n0 < 512) ? Wf : Wb;
  const int nbase = (n0 < 512) ? n0 : (n0 - 512);

  v2f acc2[8][4];
  #pragma unroll
  for (int i = 0; i < 8; ++i)
    #pragma unroll
    for (int jj = 0; jj < 4; ++jj) { acc2[i][jj].x = 0.f; acc2[i][jj].y = 0.f; }

  for (int k0 = 0; k0 < 256; k0 += 32) {
    const int gm = m0 + lrow;
    #pragma unroll
    for (int q = 0; q < 4; ++q) {
      float4 v = make_float4(0.f, 0.f, 0.f, 0.f);
      if (gm < VOCAB) v = *(const float4*)(emb + (size_t)gm * 256 + k0 + lseg + 4 * q);
      As[lseg + 4*q + 0][lrow] = v.x;
      As[lseg + 4*q + 1][lrow] = v.y;
      As[lseg + 4*q + 2][lrow] = v.z;
      As[lseg + 4*q + 3][lrow] = v.w;
    }
    #pragma unroll
    for (int q = 0; q < 4; ++q) {
      float4 v = *(const float4*)(Wsrc + (size_t)(nbase + lrow) * 256 + k0 + lseg + 4 * q);
      Bs[lseg + 4*q + 0][lrow] = v.x;
      Bs[lseg + 4*q + 1][lrow] = v.y;
      Bs[lseg + 4*q + 2][lrow] = v.z;
      Bs[lseg + 4*q + 3][lrow] = v.w;
    }
    __syncthreads();
    #pragma unroll
    for (int k = 0; k < 32; ++k) {
      float4 av0 = *(const float4*)&As[k][ty * 8];
      float4 av1 = *(const float4*)&As[k][ty * 8 + 4];
      float4 bv0 = *(const float4*)&Bs[k][tx * 4];
      float4 bv1 = *(const float4*)&Bs[k][64 + tx * 4];
      float a8[8] = {av0.x, av0.y, av0.z, av0.w, av1.x, av1.y, av1.z, av1.w};
      v2f b20, b21, b22, b23;
      b20.x = bv0.x; b20.y = bv0.y;  b21.x = bv0.z; b21.y = bv0.w;
      b22.x = bv1.x; b22.y = bv1.y;  b23.x = bv1.z; b23.y = bv1.w;
      #pragma unroll
      for (int i = 0; i < 8; ++i) {
        v2f ai; ai.x = a8[i]; ai.y = a8[i];
        acc2[i][0] = fma2(ai, b20, acc2[i][0]);
        acc2[i][1] = fma2(ai, b21, acc2[i][1]);
        acc2[i][2] = fma2(ai, b22, acc2[i][2]);
        acc2[i][3] = fma2(ai, b23, acc2[i][3]);
      }
    }
    __syncthreads();
  }

  float bias[8];
  #pragma unroll
  for (int jj = 0; jj < 8; ++jj) {
    int n = n0 + ((jj < 4) ? (tx * 4 + jj) : (64 + tx * 4 + (jj - 4)));
    bias[jj] = (n < 512) ? (bihf[n] + bhhf[n]) : (bihb[n - 512] + bhhb[n - 512]);
  }
  #pragma unroll
  for (int i = 0; i < 8; ++i) {
    int gm = m0 + ty * 8 + i;
    if (gm >= VOCAB) continue;
    float4 v0 = make_float4(acc2[i][0].x + bias[0], acc2[i][0].y + bias[1],
                            acc2[i][1].x + bias[2], acc2[i][1].y + bias[3]);
    float4 v1 = make_float4(acc2[i][2].x + bias[4], acc2[i][2].y + bias[5],
                            acc2[i][3].x + bias[6], acc2[i][3].y + bias[7]);
    *(float4*)(embW + (size_t)gm * NCOL + n0 + tx * 4) = v0;
    *(float4*)(embW + (size_t)gm * NCOL + n0 + 64 + tx * 4) = v1;
  }
}

// ---------------------------------------------------------------------------
// Kernel 2: masked LSTM recurrence. R8 structure (512 thr, waves_per_eu(2,2),
// 8-slot LDS h-ring, batched gathers, in-block emission) with two changes:
// (a) weights pinned as 64 DOUBLE pairs (64-bit tied "+v" -- the supported
//     form; R4's failure was the 128-bit tuple) and the dot computed with
//     packed v2f FMAs (v_pk_fma_f32): 64 FMA instrs/thread instead of 128.
//     Pairing keeps the accumulation order bit-identical to R8.
// (b) butterfly all-reduce (8 shfl, depth 2) replaces transpose-reduce +
//     activated-exchange (depth 4 + ~20 cndmasks): every thread gets all 4
//     gate totals, computes c/h redundantly; only q==0 writes. xw is
//     pre-added to the owning thread's partial. R8 cycle audit: 1954/step =
//     810 VALU + ~300 DS + ~850 unhidden head/tail latency -- this attacks
//     the VALU (a) and the tail (b).
// ---------------------------------------------------------------------------
#define REP8(M) M(0) M(1) M(2) M(3) M(4) M(5) M(6) M(7)
// weight decl: (gate, float4 idx, pair idx lo, pair idx hi)
#define REPD(M,G) M(G,0,0,1) M(G,1,2,3) M(G,2,4,5) M(G,3,6,7) \
                  M(G,4,8,9) M(G,5,10,11) M(G,6,12,13) M(G,7,14,15)
// MACC: (gate, pair idx, accumulator A/B) -- even pairs -> A, odd -> B
#define REPM(M,G) M(G,0,A) M(G,1,B) M(G,2,A) M(G,3,B) M(G,4,A) M(G,5,B) \
  M(G,6,A) M(G,7,B) M(G,8,A) M(G,9,B) M(G,10,A) M(G,11,B) M(G,12,A) \
  M(G,13,B) M(G,14,A) M(G,15,B)

__global__ __launch_bounds__(512)
__attribute__((amdgpu_waves_per_eu(2, 2)))
void lstm_rec(
    const int* __restrict__ pad_seq, const int* __restrict__ lens,
    const float* __restrict__ Whh_f, const float* __restrict__ Whh_b,
    const float* __restrict__ embW, const float* __restrict__ W_lab,
    float* __restrict__ e_part) {
  const int dir = blockIdx.x & 1;
  const int b   = blockIdx.x >> 1;
  const int tid = threadIdx.x;
  const int j   = tid >> 2;      // hidden unit 0..127
  const int q   = tid & 3;       // K-quarter owner / xw gate owner 0..3

  __shared__ float ring[8][4][36];   // [slot][chunk][32 + 4 pad]
  __shared__ float wls[4][132];      // W_lab cols for MY direction, padded
  __shared__ int   tok[TMAX];

  tok[tid] = pad_seq[b * TMAX + tid];
  wls[tid >> 7][tid & 127] = W_lab[(tid >> 7) * DIM + dir * HID + (tid & 127)];
  if (tid < 144) ((float*)ring)[tid] = 0.f;    // slot 0 = h(-1) = 0

  const int len = lens[b];
  const float* __restrict__ Whh = dir ? Whh_b : Whh_f;

  // W_hh: 4 gate rows x 32 cols = 64 pinned 64-bit pairs (128 VGPRs)
  const float4* wr0 = (const float4*)(Whh + (size_t)(0 * HID + j) * HID + 32 * q);
  const float4* wr1 = (const float4*)(Whh + (size_t)(1 * HID + j) * HID + 32 * q);
  const float4* wr2 = (const float4*)(Whh + (size_t)(2 * HID + j) * HID + 32 * q);
  const float4* wr3 = (const float4*)(Whh + (size_t)(3 * HID + j) * HID + 32 * q);
#define DECLW(G,I,PA,PB)                                                \
  v2f wp##G##_##PA, wp##G##_##PB;                                       \
  { float4 t = wr##G[I];                                                \
    v2f vA; vA.x = t.x; vA.y = t.y;                                     \
    v2f vB; vB.x = t.z; vB.y = t.w;                                     \
    double dA = __builtin_bit_cast(double, vA);                         \
    double dB = __builtin_bit_cast(double, vB);                         \
    asm volatile("" : "+v"(dA));                                        \
    asm volatile("" : "+v"(dB));                                        \
    wp##G##_##PA = __builtin_bit_cast(v2f, dA);                         \
    wp##G##_##PB = __builtin_bit_cast(v2f, dB); }
  REPD(DECLW,0) REPD(DECLW,1) REPD(DECLW,2) REPD(DECLW,3)
#undef DECLW

  float c = 0.f;
  const float* __restrict__ ecol = embW + dir * G4 + (q * HID + j);
  float* __restrict__ ep = e_part + (size_t)(dir * BATCH + b) * TMAX * 4;

  __syncthreads();

  // batched x@Wih gathers for the next 8 steps (one vmcnt drain per group)
  float xb0, xb1, xb2, xb3, xb4, xb5, xb6, xb7;
#define PRE(r) { const int ss = nbase + r; xb##r = 0.f;                 \
    if (ss < len) {                                                     \
      const int tt = dir ? (len - 1 - ss) : ss;                         \
      xb##r = ecol[(size_t)tok[tt] * NCOL]; } }
  { const int nbase = 0; REP8(PRE) }

#define MACC(G,K,AB) ac##G##AB = fma2(hp##K, wp##G##_##K, ac##G##AB);
#define HPAIR(K,F,S0,S1) v2f hp##K; hp##K.x = F.S0; hp##K.y = F.S1;

#define STEP(r, XW)                                                     \
  {                                                                     \
    const float4* h4 = (const float4*)&ring[r][q][0];                   \
    float4 f0=h4[0], f1=h4[1], f2=h4[2], f3=h4[3];                      \
    float4 f4=h4[4], f5=h4[5], f6=h4[6], f7=h4[7];                      \
    HPAIR(0,f0,x,y)  HPAIR(1,f0,z,w)  HPAIR(2,f1,x,y)  HPAIR(3,f1,z,w)  \
    HPAIR(4,f2,x,y)  HPAIR(5,f2,z,w)  HPAIR(6,f3,x,y)  HPAIR(7,f3,z,w)  \
    HPAIR(8,f4,x,y)  HPAIR(9,f4,z,w)  HPAIR(10,f5,x,y) HPAIR(11,f5,z,w) \
    HPAIR(12,f6,x,y) HPAIR(13,f6,z,w) HPAIR(14,f7,x,y) HPAIR(15,f7,z,w) \
    v2f ac0A = {0.f,0.f}, ac0B = {0.f,0.f};                             \
    v2f ac1A = {0.f,0.f}, ac1B = {0.f,0.f};                             \
    v2f ac2A = {0.f,0.f}, ac2B = {0.f,0.f};                             \
    v2f ac3A = {0.f,0.f}, ac3B = {0.f,0.f};                             \
    REPM(MACC,0) REPM(MACC,1) REPM(MACC,2) REPM(MACC,3)                 \
    float p0 = (ac0A.x + ac0A.y) + (ac0B.x + ac0B.y);                   \
    float p1 = (ac1A.x + ac1A.y) + (ac1B.x + ac1B.y);                   \
    float p2 = (ac2A.x + ac2A.y) + (ac2B.x + ac2B.y);                   \
    float p3 = (ac3A.x + ac3A.y) + (ac3B.x + ac3B.y);                   \
    /* owner pre-adds its xw so each gate total contains it exactly once */ \
    p0 += (q == 0) ? (XW) : 0.f;                                        \
    p1 += (q == 1) ? (XW) : 0.f;                                        \
    p2 += (q == 2) ? (XW) : 0.f;                                        \
    p3 += (q == 3) ? (XW) : 0.f;                                        \
    /* butterfly all-reduce across the quad: depth 2 */                 \
    p0 += __shfl_xor(p0, 1); p1 += __shfl_xor(p1, 1);                   \
    p2 += __shfl_xor(p2, 1); p3 += __shfl_xor(p3, 1);                   \
    p0 += __shfl_xor(p0, 2); p1 += __shfl_xor(p1, 2);                   \
    p2 += __shfl_xor(p2, 2); p3 += __shfl_xor(p3, 2);                   \
    const float ig = 1.f / (1.f + __expf(-p0));                         \
    const float fg = 1.f / (1.f + __expf(-p1));                         \
    const float sgg = 1.f / (1.f + __expf(-2.f * p2));                  \
    const float gt = 2.f * sgg - 1.f;                                   \
    const float og = 1.f / (1.f + __expf(-p3));                         \
    c = fg * c + ig * gt;                                               \
    const float s2 = 1.f / (1.f + __expf(-2.f * c));                    \
    const float hh = og * (2.f * s2 - 1.f);                             \
    if (q == 0) ring[(r + 1) & 7][j >> 5][j & 31] = hh;                 \
    __syncthreads();                                                    \
  }

  for (int s0 = 0; s0 < len; s0 += 8) {
    const int cnt = (len - s0 < 8) ? (len - s0) : 8;   // block-uniform
    STEP(0, xb0)
    if (cnt > 1) STEP(1, xb1)
    if (cnt > 2) STEP(2, xb2)
    if (cnt > 3) STEP(3, xb3)
    if (cnt > 4) STEP(4, xb4)
    if (cnt > 5) STEP(5, xb5)
    if (cnt > 6) STEP(6, xb6)
    if (cnt > 7) STEP(7, xb7)
    // prefetch next group's gathers (drain amortized at the group barrier)
    { const int nbase = s0 + 8; REP8(PRE) }
    // emission partials for this group: (r,l,sub) = 8x4x16 = 512 threads
    {
      const int r = tid >> 6, l = (tid >> 4) & 3, sub = tid & 15;
      if (r < cnt) {                        // wave-uniform (r const per wave)
        const float4* hp = (const float4*)&ring[(r + 1) & 7][sub >> 2][8 * (sub & 3)];
        const float4 h0 = hp[0], h1 = hp[1];
        const float4* wp = (const float4*)&wls[l][8 * sub];
        const float4 u0 = wp[0], u1 = wp[1];
        float d = h0.x*u0.x + h0.y*u0.y + h0.z*u0.z + h0.w*u0.w
                + h1.x*u1.x + h1.y*u1.y + h1.z*u1.z + h1.w*u1.w;
        d += __shfl_xor(d, 1); d += __shfl_xor(d, 2);
        d += __shfl_xor(d, 4); d += __shfl_xor(d, 8);
        if (sub == 0) {
          const int ss = s0 + r;
          const int tt = dir ? (len - 1 - ss) : ss;
          ep[tt * 4 + l] = d;
        }
      }
    }
    asm volatile("" : "+v"(xb0), "+v"(xb1), "+v"(xb2), "+v"(xb3),
                      "+v"(xb4), "+v"(xb5), "+v"(xb6), "+v"(xb7));
    __syncthreads();
  }
#undef STEP
#undef MACC
#undef HPAIR
#undef PRE
}

// ---------------------------------------------------------------------------
// Kernel 3: Viterbi only (emissions pre-reduced into e_part by lstm_rec).
// ---------------------------------------------------------------------------
__global__ __launch_bounds__(512) void viterbi_k(
    const int* __restrict__ lens, const float* __restrict__ e_part,
    const float* __restrict__ b_lab, const float* __restrict__ trans,
    const float* __restrict__ from_BOS, const float* __restrict__ to_EOS,
    int* __restrict__ out) {
  const int b = blockIdx.x;
  const int tid = threadIdx.x;
  __shared__ float sc[TMAX][4];
  __shared__ unsigned btm[TMAX];
  __shared__ int labs[TMAX];
  const int len = lens[b];

  if (tid < len) {
    const float4 f  = *(const float4*)(e_part + ((size_t)b * TMAX + tid) * 4);
    const float4 g2 = *(const float4*)(e_part + ((size_t)(BATCH + b) * TMAX + tid) * 4);
    const float4 bl = *(const float4*)b_lab;
    sc[tid][0] = f.x + g2.x + bl.x;
    sc[tid][1] = f.y + g2.y + bl.y;
    sc[tid][2] = f.z + g2.z + bl.z;
    sc[tid][3] = f.w + g2.w + bl.w;
  }
  __syncthreads();

  // --- DP: lanes 0..3 of wave 0, lane l owns cur-label l ---
  if (tid < 4) {
    const int l = tid;
    float trc0 = trans[0 * 4 + l], trc1 = trans[1 * 4 + l];
    float trc2 = trans[2 * 4 + l], trc3 = trans[3 * 4 + l];
    float best = from_BOS[l] + sc[0][l];
    float e_next = sc[1][l];
    for (int ti = 1; ti < len; ++ti) {
      const float e = e_next;
      e_next = sc[(ti + 1 < TMAX) ? ti + 1 : ti][l];
      const float b0 = __shfl(best, 0);
      const float b1 = __shfl(best, 1);
      const float b2 = __shfl(best, 2);
      const float b3 = __shfl(best, 3);
      // reference add order: (best[p] + e[cur]) + trans[p][cur]; first-max
      float m = (b0 + e) + trc0; int arg = 0;
      float v;
      v = (b1 + e) + trc1; if (v > m) { m = v; arg = 1; }
      v = (b2 + e) + trc2; if (v > m) { m = v; arg = 2; }
      v = (b3 + e) + trc3; if (v > m) { m = v; arg = 3; }
      best = m;
      unsigned av = ((unsigned)arg) << (8 * l);
      av |= __shfl_xor(av, 1);
      av |= __shfl_xor(av, 2);
      if (l == 0) btm[ti] = av;
    }
    const float f0 = __shfl(best, 0) + to_EOS[0];
    const float f1 = __shfl(best, 1) + to_EOS[1];
    const float f2 = __shfl(best, 2) + to_EOS[2];
    const float f3 = __shfl(best, 3) + to_EOS[3];
    if (l == 0) {
      float m = f0; int last = 0;
      if (f1 > m) { m = f1; last = 1; }
      if (f2 > m) { m = f2; last = 2; }
      if (f3 > m) { m = f3; last = 3; }
      labs[len - 1] = last;
      int cur = last;
      #pragma unroll 4
      for (int ti = len - 2; ti >= 0; --ti) {
        cur = (int)((btm[ti + 1] >> (8 * cur)) & 255u);
        labs[ti] = cur;
      }
    }
  }
  __syncthreads();
  out[b * TMAX + tid] = (tid < len) ? labs[tid] : 0;
}

// ---------------------------------------------------------------------------
extern "C" void kernel_launch(void* const* d_in, const int* in_sizes, int n_in,
                              void* d_out, int out_size, void* d_ws, size_t ws_size,
                              hipStream_t stream) {
  const int*   pad_seq  = (const int*)d_in[0];
  const int*   lens     = (const int*)d_in[1];
  const float* emb      = (const float*)d_in[2];
  const float* W_ih_f   = (const float*)d_in[3];
  const float* W_hh_f   = (const float*)d_in[4];
  const float* b_ih_f   = (const float*)d_in[5];
  const float* b_hh_f   = (const float*)d_in[6];
  const float* W_ih_b   = (const float*)d_in[7];
  const float* W_hh_b   = (const float*)d_in[8];
  const float* b_ih_b   = (const float*)d_in[9];
  const float* b_hh_b   = (const float*)d_in[10];
  const float* W_lab    = (const float*)d_in[11];
  const float* b_lab    = (const float*)d_in[12];
  const float* trans    = (const float*)d_in[13];
  const float* from_BOS = (const float*)d_in[14];
  const float* to_EOS   = (const float*)d_in[15];
  int* out = (int*)d_out;

  float* embW   = (float*)d_ws;                      // [8000][1024] = 32.8 MB
  float* e_part = embW + (size_t)VOCAB * NCOL;       // [2][B][T][4] = 2 MB

  embw_gemm<<<dim3(63, 8), 256, 0, stream>>>(emb, W_ih_f, W_ih_b,
                                             b_ih_f, b_hh_f, b_ih_b, b_hh_b, embW);
  lstm_rec<<<dim3(2 * BATCH), 512, 0, stream>>>(pad_seq, lens, W_hh_f, W_hh_b,
                                                embW, W_lab, e_part);
  viterbi_k<<<dim3(BATCH), 512, 0, stream>>>(lens, e_part, b_lab, trans,
                                             from_BOS, to_EOS, out);
}

// Round 10
// 581.676 us; speedup vs baseline: 1.2467x; 1.2467x over previous
//
#include <hip/hip_runtime.h>
#include <math.h>

#define VOCAB 8000
#define BATCH 128
#define TMAX  512
#define DIM   256
#define HID   128
#define G4    512     // 4*HID
#define NCOL  1024    // 2*G4 (both directions)

// --- DPP quad-lane ops: VALU-speed (~4cyc) replacements for __shfl within a
// quad (which lowers to ds_swizzle/ds_bpermute on the LDS pipe, ~50-120cyc).
// quad_perm ctrl = sel0 | sel1<<2 | sel2<<4 | sel3<<6.
__device__ __forceinline__ float dpp_xor1(float x) {   // [1,0,3,2] = 0xB1
  int r = __builtin_amdgcn_update_dpp(0, __builtin_bit_cast(int, x),
                                      0xB1, 0xF, 0xF, true);
  return __builtin_bit_cast(float, r);
}
__device__ __forceinline__ float dpp_xor2(float x) {   // [2,3,0,1] = 0x4E
  int r = __builtin_amdgcn_update_dpp(0, __builtin_bit_cast(int, x),
                                      0x4E, 0xF, 0xF, true);
  return __builtin_bit_cast(float, r);
}
__device__ __forceinline__ unsigned dpp_xor1u(unsigned x) {
  return (unsigned)__builtin_amdgcn_update_dpp(0, (int)x, 0xB1, 0xF, 0xF, true);
}
__device__ __forceinline__ unsigned dpp_xor2u(unsigned x) {
  return (unsigned)__builtin_amdgcn_update_dpp(0, (int)x, 0x4E, 0xF, 0xF, true);
}
__device__ __forceinline__ float dpp_bc0(float x) {    // broadcast quad lane 0
  int r = __builtin_amdgcn_update_dpp(0, __builtin_bit_cast(int, x),
                                      0x00, 0xF, 0xF, true);
  return __builtin_bit_cast(float, r);
}
__device__ __forceinline__ float dpp_bc1(float x) {
  int r = __builtin_amdgcn_update_dpp(0, __builtin_bit_cast(int, x),
                                      0x55, 0xF, 0xF, true);
  return __builtin_bit_cast(float, r);
}
__device__ __forceinline__ float dpp_bc2(float x) {
  int r = __builtin_amdgcn_update_dpp(0, __builtin_bit_cast(int, x),
                                      0xAA, 0xF, 0xF, true);
  return __builtin_bit_cast(float, r);
}
__device__ __forceinline__ float dpp_bc3(float x) {
  int r = __builtin_amdgcn_update_dpp(0, __builtin_bit_cast(int, x),
                                      0xFF, 0xF, 0xF, true);
  return __builtin_bit_cast(float, r);
}

// ---------------------------------------------------------------------------
// Kernel 1: embW[v][n] = emb[v,:] . W_ih_dir[n,:] + b_ih_dir[n] + b_hh_dir[n]
// (R8 scalar version -- R9's pk_fma variant was neutral; pk fp32 doesn't
// raise FLOP rate on CDNA4.)
// ---------------------------------------------------------------------------
__global__ __launch_bounds__(256) void embw_gemm(
    const float* __restrict__ emb,
    const float* __restrict__ Wf, const float* __restrict__ Wb,
    const float* __restrict__ bihf, const float* __restrict__ bhhf,
    const float* __restrict__ bihb, const float* __restrict__ bhhb,
    float* __restrict__ embW) {
  __shared__ float As[32][132];   // k-major, padded stride
  __shared__ float Bs[32][132];
  const int tid = threadIdx.x;
  const int m0 = blockIdx.x * 128;
  const int n0 = blockIdx.y * 128;
  const int tx = tid & 15, ty = tid >> 4;
  const int lrow = tid >> 1;            // 0..127
  const int lseg = (tid & 1) * 16;      // 0 or 16 (k offset)
  const float* Wsrc = (n0 < 512) ? Wf : Wb;
  const int nbase = (n0 < 512) ? n0 : (n0 - 512);

  float acc[8][8];
  #pragma unroll
  for (int i = 0; i < 8; ++i)
    #pragma unroll
    for (int jj = 0; jj < 8; ++jj) acc[i][jj] = 0.f;

  for (int k0 = 0; k0 < 256; k0 += 32) {
    const int gm = m0 + lrow;
    #pragma unroll
    for (int q = 0; q < 4; ++q) {
      float4 v = make_float4(0.f, 0.f, 0.f, 0.f);
      if (gm < VOCAB) v = *(const float4*)(emb + (size_t)gm * 256 + k0 + lseg + 4 * q);
      As[lseg + 4*q + 0][lrow] = v.x;
      As[lseg + 4*q + 1][lrow] = v.y;
      As[lseg + 4*q + 2][lrow] = v.z;
      As[lseg + 4*q + 3][lrow] = v.w;
    }
    #pragma unroll
    for (int q = 0; q < 4; ++q) {
      float4 v = *(const float4*)(Wsrc + (size_t)(nbase + lrow) * 256 + k0 + lseg + 4 * q);
      Bs[lseg + 4*q + 0][lrow] = v.x;
      Bs[lseg + 4*q + 1][lrow] = v.y;
      Bs[lseg + 4*q + 2][lrow] = v.z;
      Bs[lseg + 4*q + 3][lrow] = v.w;
    }
    __syncthreads();
    #pragma unroll
    for (int k = 0; k < 32; ++k) {
      float4 av0 = *(const float4*)&As[k][ty * 8];
      float4 av1 = *(const float4*)&As[k][ty * 8 + 4];
      float4 bv0 = *(const float4*)&Bs[k][tx * 4];
      float4 bv1 = *(const float4*)&Bs[k][64 + tx * 4];
      float a[8]  = {av0.x, av0.y, av0.z, av0.w, av1.x, av1.y, av1.z, av1.w};
      float bb[8] = {bv0.x, bv0.y, bv0.z, bv0.w, bv1.x, bv1.y, bv1.z, bv1.w};
      #pragma unroll
      for (int i = 0; i < 8; ++i)
        #pragma unroll
        for (int jj = 0; jj < 8; ++jj)
          acc[i][jj] += a[i] * bb[jj];
    }
    __syncthreads();
  }

  float bias[8];
  #pragma unroll
  for (int jj = 0; jj < 8; ++jj) {
    int n = n0 + ((jj < 4) ? (tx * 4 + jj) : (64 + tx * 4 + (jj - 4)));
    bias[jj] = (n < 512) ? (bihf[n] + bhhf[n]) : (bihb[n - 512] + bhhb[n - 512]);
  }
  #pragma unroll
  for (int i = 0; i < 8; ++i) {
    int gm = m0 + ty * 8 + i;
    if (gm >= VOCAB) continue;
    float4 v0 = make_float4(acc[i][0] + bias[0], acc[i][1] + bias[1],
                            acc[i][2] + bias[2], acc[i][3] + bias[3]);
    float4 v1 = make_float4(acc[i][4] + bias[4], acc[i][5] + bias[5],
                            acc[i][6] + bias[6], acc[i][7] + bias[7]);
    *(float4*)(embW + (size_t)gm * NCOL + n0 + tx * 4) = v0;
    *(float4*)(embW + (size_t)gm * NCOL + n0 + 64 + tx * 4) = v1;
  }
}

// ---------------------------------------------------------------------------
// Kernel 2: masked LSTM recurrence. Exact R8 structure (512 thr,
// waves_per_eu(2,2), 128 asm-pinned scalar weights, 8-slot LDS h-ring,
// batched gathers, in-block emissions) with ONE change: the 6 intra-quad
// __shfl_xor on the per-step critical path (reduce + gate exchange) become
// DPP quad_perm ops. R8 audit: 1954 cyc/step = 810 VALU + ~300 DS + ~850
// unhidden latency, of which ~200-400 was ds_bpermute shuffle latency.
// (R9 lesson: pk_fma_f32 does NOT raise fp32 FLOP rate on CDNA4 -- reverted.)
// ---------------------------------------------------------------------------
#define REP8(M) M(0) M(1) M(2) M(3) M(4) M(5) M(6) M(7)
#define REP8G(M,G) M(G,0) M(G,1) M(G,2) M(G,3) M(G,4) M(G,5) M(G,6) M(G,7)

__global__ __launch_bounds__(512)
__attribute__((amdgpu_waves_per_eu(2, 2)))
void lstm_rec(
    const int* __restrict__ pad_seq, const int* __restrict__ lens,
    const float* __restrict__ Whh_f, const float* __restrict__ Whh_b,
    const float* __restrict__ embW, const float* __restrict__ W_lab,
    float* __restrict__ e_part) {
  const int dir = blockIdx.x & 1;
  const int b   = blockIdx.x >> 1;
  const int tid = threadIdx.x;
  const int j   = tid >> 2;      // hidden unit 0..127
  const int q   = tid & 3;       // K-quarter / gate owner 0..3
  const int parity = q & 1;
  const int half   = (q >> 1) & 1;

  __shared__ float ring[8][4][36];   // [slot][chunk][32 + 4 pad]
  __shared__ float wls[4][132];      // W_lab cols for MY direction, padded
  __shared__ int   tok[TMAX];

  tok[tid] = pad_seq[b * TMAX + tid];
  wls[tid >> 7][tid & 127] = W_lab[(tid >> 7) * DIM + dir * HID + (tid & 127)];
  if (tid < 144) ((float*)ring)[tid] = 0.f;    // slot 0 = h(-1) = 0

  const int len = lens[b];
  const float* __restrict__ Whh = dir ? Whh_b : Whh_f;

  // W_hh: 4 gate rows x 32 cols = 128 pinned scalars (R5/R6/R8-proven idiom)
  const float4* wr0 = (const float4*)(Whh + (size_t)(0 * HID + j) * HID + 32 * q);
  const float4* wr1 = (const float4*)(Whh + (size_t)(1 * HID + j) * HID + 32 * q);
  const float4* wr2 = (const float4*)(Whh + (size_t)(2 * HID + j) * HID + 32 * q);
  const float4* wr3 = (const float4*)(Whh + (size_t)(3 * HID + j) * HID + 32 * q);
#define DECLW(G,I)                                                      \
  float w##G##_##I##_0, w##G##_##I##_1, w##G##_##I##_2, w##G##_##I##_3; \
  { float4 t = wr##G[I];                                                \
    w##G##_##I##_0 = t.x; w##G##_##I##_1 = t.y;                         \
    w##G##_##I##_2 = t.z; w##G##_##I##_3 = t.w; }                       \
  asm volatile("" : "+v"(w##G##_##I##_0));                              \
  asm volatile("" : "+v"(w##G##_##I##_1));                              \
  asm volatile("" : "+v"(w##G##_##I##_2));                              \
  asm volatile("" : "+v"(w##G##_##I##_3));
  REP8G(DECLW,0) REP8G(DECLW,1) REP8G(DECLW,2) REP8G(DECLW,3)
#undef DECLW

  float c = 0.f;
  const float ascale = (q == 2) ? 2.f : 1.f;     // tanh(x)=2*sig(2x)-1 for g
  const float* __restrict__ ecol = embW + dir * G4 + (q * HID + j);
  float* __restrict__ ep = e_part + (size_t)(dir * BATCH + b) * TMAX * 4;

  __syncthreads();

  // batched x@Wih gathers for the next 8 steps (one vmcnt drain per group)
  float xb0, xb1, xb2, xb3, xb4, xb5, xb6, xb7;
#define PRE(r) { const int ss = nbase + r; xb##r = 0.f;                 \
    if (ss < len) {                                                     \
      const int tt = dir ? (len - 1 - ss) : ss;                         \
      xb##r = ecol[(size_t)tok[tt] * NCOL]; } }
  { const int nbase = 0; REP8(PRE) }

#define MACC(G,I)                                         \
    a##G##0 = fmaf(hv##I.x, w##G##_##I##_0, a##G##0);     \
    a##G##1 = fmaf(hv##I.y, w##G##_##I##_1, a##G##1);     \
    a##G##2 = fmaf(hv##I.z, w##G##_##I##_2, a##G##2);     \
    a##G##3 = fmaf(hv##I.w, w##G##_##I##_3, a##G##3);

#define STEP(r, XW)                                                     \
  {                                                                     \
    const float4* h4 = (const float4*)&ring[r][q][0];                   \
    float4 hv0 = h4[0], hv1 = h4[1], hv2 = h4[2], hv3 = h4[3];          \
    float4 hv4 = h4[4], hv5 = h4[5], hv6 = h4[6], hv7 = h4[7];          \
    float a00=0.f,a01=0.f,a02=0.f,a03=0.f;                              \
    float a10=0.f,a11=0.f,a12=0.f,a13=0.f;                              \
    float a20=0.f,a21=0.f,a22=0.f,a23=0.f;                              \
    float a30=0.f,a31=0.f,a32=0.f,a33=0.f;                              \
    REP8G(MACC,0) REP8G(MACC,1) REP8G(MACC,2) REP8G(MACC,3)             \
    const float p0 = (a00+a01)+(a02+a03);                               \
    const float p1 = (a10+a11)+(a12+a13);                               \
    const float p2 = (a20+a21)+(a22+a23);                               \
    const float p3 = (a30+a31)+(a32+a33);                               \
    /* quad transpose-reduce via DPP: thread q ends with gate q's total */ \
    const float klo = parity ? p1 : p0, slo = parity ? p0 : p1;         \
    const float khi = parity ? p3 : p2, shi = parity ? p2 : p3;         \
    const float alo = klo + dpp_xor1(slo);                              \
    const float ahi = khi + dpp_xor1(shi);                              \
    const float kb = half ? ahi : alo, sb = half ? alo : ahi;           \
    const float tot = kb + dpp_xor2(sb);                                \
    const float aa = tot + (XW);                                        \
    const float sg = 1.f / (1.f + __expf(-ascale * aa));                \
    const float act = (q == 2) ? (2.f * sg - 1.f) : sg;                 \
    /* quad exchange of ACTIVATED gates via DPP */                      \
    const float e1 = dpp_xor1(act);                                     \
    const float e2 = dpp_xor2(act);                                     \
    const float e3 = dpp_xor2(e1);                                      \
    const float ev  = parity ? e1 : act, od  = parity ? act : e1;       \
    const float ev2 = parity ? e3 : e2,  od2 = parity ? e2 : e3;        \
    const float ig = half ? ev2 : ev, fg = half ? od2 : od;             \
    const float gt = half ? ev : ev2, og = half ? od : od2;             \
    c = fg * c + ig * gt;                                               \
    const float s2 = 1.f / (1.f + __expf(-2.f * c));                    \
    const float hh = og * (2.f * s2 - 1.f);                             \
    if (q == 0) ring[(r + 1) & 7][j >> 5][j & 31] = hh;                 \
    __syncthreads();                                                    \
  }

  for (int s0 = 0; s0 < len; s0 += 8) {
    const int cnt = (len - s0 < 8) ? (len - s0) : 8;   // block-uniform
    STEP(0, xb0)
    if (cnt > 1) STEP(1, xb1)
    if (cnt > 2) STEP(2, xb2)
    if (cnt > 3) STEP(3, xb3)
    if (cnt > 4) STEP(4, xb4)
    if (cnt > 5) STEP(5, xb5)
    if (cnt > 6) STEP(6, xb6)
    if (cnt > 7) STEP(7, xb7)
    // prefetch next group's gathers (drain amortized at the group barrier)
    { const int nbase = s0 + 8; REP8(PRE) }
    // emission partials for this group: (r,l,sub) = 8x4x16 = 512 threads
    {
      const int r = tid >> 6, l = (tid >> 4) & 3, sub = tid & 15;
      if (r < cnt) {                        // wave-uniform (r const per wave)
        const float4* hp = (const float4*)&ring[(r + 1) & 7][sub >> 2][8 * (sub & 3)];
        const float4 h0 = hp[0], h1 = hp[1];
        const float4* wp = (const float4*)&wls[l][8 * sub];
        const float4 u0 = wp[0], u1 = wp[1];
        float d = h0.x*u0.x + h0.y*u0.y + h0.z*u0.z + h0.w*u0.w
                + h1.x*u1.x + h1.y*u1.y + h1.z*u1.z + h1.w*u1.w;
        d += __shfl_xor(d, 1); d += __shfl_xor(d, 2);
        d += __shfl_xor(d, 4); d += __shfl_xor(d, 8);
        if (sub == 0) {
          const int ss = s0 + r;
          const int tt = dir ? (len - 1 - ss) : ss;
          ep[tt * 4 + l] = d;
        }
      }
    }
    asm volatile("" : "+v"(xb0), "+v"(xb1), "+v"(xb2), "+v"(xb3),
                      "+v"(xb4), "+v"(xb5), "+v"(xb6), "+v"(xb7));
    __syncthreads();
  }
#undef STEP
#undef MACC
#undef PRE
}

// ---------------------------------------------------------------------------
// Kernel 3: Viterbi (emissions pre-reduced into e_part by lstm_rec).
// DP quad broadcasts + backtrace packing via DPP (VALU-speed lane ops).
// ---------------------------------------------------------------------------
__global__ __launch_bounds__(512) void viterbi_k(
    const int* __restrict__ lens, const float* __restrict__ e_part,
    const float* __restrict__ b_lab, const float* __restrict__ trans,
    const float* __restrict__ from_BOS, const float* __restrict__ to_EOS,
    int* __restrict__ out) {
  const int b = blockIdx.x;
  const int tid = threadIdx.x;
  __shared__ float sc[TMAX][4];
  __shared__ unsigned btm[TMAX];
  __shared__ int labs[TMAX];
  const int len = lens[b];

  if (tid < len) {
    const float4 f  = *(const float4*)(e_part + ((size_t)b * TMAX + tid) * 4);
    const float4 g2 = *(const float4*)(e_part + ((size_t)(BATCH + b) * TMAX + tid) * 4);
    const float4 bl = *(const float4*)b_lab;
    sc[tid][0] = f.x + g2.x + bl.x;
    sc[tid][1] = f.y + g2.y + bl.y;
    sc[tid][2] = f.z + g2.z + bl.z;
    sc[tid][3] = f.w + g2.w + bl.w;
  }
  __syncthreads();

  // --- DP: lanes 0..3 of wave 0, lane l owns cur-label l ---
  if (tid < 4) {
    const int l = tid;
    float trc0 = trans[0 * 4 + l], trc1 = trans[1 * 4 + l];
    float trc2 = trans[2 * 4 + l], trc3 = trans[3 * 4 + l];
    float best = from_BOS[l] + sc[0][l];
    float e_next = sc[1][l];
    for (int ti = 1; ti < len; ++ti) {
      const float e = e_next;
      e_next = sc[(ti + 1 < TMAX) ? ti + 1 : ti][l];
      const float b0 = dpp_bc0(best);
      const float b1 = dpp_bc1(best);
      const float b2 = dpp_bc2(best);
      const float b3 = dpp_bc3(best);
      // reference add order: (best[p] + e[cur]) + trans[p][cur]; first-max
      float m = (b0 + e) + trc0; int arg = 0;
      float v;
      v = (b1 + e) + trc1; if (v > m) { m = v; arg = 1; }
      v = (b2 + e) + trc2; if (v > m) { m = v; arg = 2; }
      v = (b3 + e) + trc3; if (v > m) { m = v; arg = 3; }
      best = m;
      unsigned av = ((unsigned)arg) << (8 * l);
      av |= dpp_xor1u(av);
      av |= dpp_xor2u(av);
      if (l == 0) btm[ti] = av;
    }
    const float f0 = dpp_bc0(best) + to_EOS[0];
    const float f1 = dpp_bc1(best) + to_EOS[1];
    const float f2 = dpp_bc2(best) + to_EOS[2];
    const float f3 = dpp_bc3(best) + to_EOS[3];
    if (l == 0) {
      float m = f0; int last = 0;
      if (f1 > m) { m = f1; last = 1; }
      if (f2 > m) { m = f2; last = 2; }
      if (f3 > m) { m = f3; last = 3; }
      labs[len - 1] = last;
      int cur = last;
      #pragma unroll 4
      for (int ti = len - 2; ti >= 0; --ti) {
        cur = (int)((btm[ti + 1] >> (8 * cur)) & 255u);
        labs[ti] = cur;
      }
    }
  }
  __syncthreads();
  out[b * TMAX + tid] = (tid < len) ? labs[tid] : 0;
}

// ---------------------------------------------------------------------------
extern "C" void kernel_launch(void* const* d_in, const int* in_sizes, int n_in,
                              void* d_out, int out_size, void* d_ws, size_t ws_size,
                              hipStream_t stream) {
  const int*   pad_seq  = (const int*)d_in[0];
  const int*   lens     = (const int*)d_in[1];
  const float* emb      = (const float*)d_in[2];
  const float* W_ih_f   = (const float*)d_in[3];
  const float* W_hh_f   = (const float*)d_in[4];
  const float* b_ih_f   = (const float*)d_in[5];
  const float* b_hh_f   = (const float*)d_in[6];
  const float* W_ih_b   = (const float*)d_in[7];
  const float* W_hh_b   = (const float*)d_in[8];
  const float* b_ih_b   = (const float*)d_in[9];
  const float* b_hh_b   = (const float*)d_in[10];
  const float* W_lab    = (const float*)d_in[11];
  const float* b_lab    = (const float*)d_in[12];
  const float* trans    = (const float*)d_in[13];
  const float* from_BOS = (const float*)d_in[14];
  const float* to_EOS   = (const float*)d_in[15];
  int* out = (int*)d_out;

  float* embW   = (float*)d_ws;                      // [8000][1024] = 32.8 MB
  float* e_part = embW + (size_t)VOCAB * NCOL;       // [2][B][T][4] = 2 MB

  embw_gemm<<<dim3(63, 8), 256, 0, stream>>>(emb, W_ih_f, W_ih_b,
                                             b_ih_f, b_hh_f, b_ih_b, b_hh_b, embW);
  lstm_rec<<<dim3(2 * BATCH), 512, 0, stream>>>(pad_seq, lens, W_hh_f, W_hh_b,
                                                embW, W_lab, e_part);
  viterbi_k<<<dim3(BATCH), 512, 0, stream>>>(lens, e_part, b_lab, trans,
                                             from_BOS, to_EOS, out);
}